// Round 2
// baseline (492.497 us; speedup 1.0000x reference)
//
#include <hip/hip_runtime.h>
#include <stdint.h>

#define N_IDS   1000000
#define ZCH     400000
#define EMB_DIM 128
#define TOTAL   (2 * N_IDS)
#define BLOCK   256
#define GRID    ((TOTAL + BLOCK - 1) / BLOCK)   // 7813

// Output buffer is FLOAT32: [0] = loss, [1 .. 2M] = remapped indices as floats.
// (Reference outputs are f32 + int32 -> harness materializes d_out as float*.)

__global__ __launch_bounds__(BLOCK) void remap_loss_kernel(
    const int* __restrict__ ids0, const int* __restrict__ ids1,
    const int* __restrict__ mch0, const int* __restrict__ mch1,
    const float* __restrict__ emb0, const float* __restrict__ emb1,
    float* __restrict__ out,        // d_out (float32)
    float* __restrict__ partials)   // d_ws: one float per block
{
    const int gid  = blockIdx.x * BLOCK + threadIdx.x;
    const int lane = threadIdx.x & 63;
    const int wave = threadIdx.x >> 6;

    float accl = 0.0f;

    // `active` is wave-uniform: TOTAL % 64 == 0, N_IDS % 64 == 0, so a wave
    // never straddles the valid/invalid or feature-0/feature-1 boundary.
    const bool active = (gid < TOTAL);
    if (active) {
        const int feat = gid >= N_IDS;
        const int i    = feat ? (gid - N_IDS) : gid;
        const int id   = (feat ? ids1 : ids0)[i];
        const int* __restrict__ mch = feat ? mch1 : mch0;
        const float* __restrict__ emb = feat ? emb1 : emb0;

        // lower_bound (searchsorted-left) over the sorted 400K table
        int lo = 0, hi = ZCH;
        #pragma unroll 1
        while (lo < hi) {
            int mid = (lo + hi) >> 1;
            if (mch[mid] < id) lo = mid + 1; else hi = mid;
        }
        int pos = (lo < ZCH) ? lo : (ZCH - 1);
        int rem = (mch[pos] == id) ? pos : (ZCH - 1);

        out[1 + gid] = (float)rem;   // exact: rem < 2^24

        // Wave-cooperative gather + partial loss sum: the wave covers its 64
        // lanes' rows; two rows per iteration via float4 (half-wave per row).
        const int half = lane >> 5;   // 0: row j, 1: row j+1
        const int l32  = lane & 31;   // 32 lanes x float4 = 512 B = one row
        #pragma unroll 1
        for (int j = 0; j < 64; j += 2) {
            int r = __shfl(rem, j + half, 64);
            const float4* __restrict__ row =
                (const float4*)(emb + (size_t)r * EMB_DIM);
            float4 v = row[l32];
            accl += (v.x + v.y) + (v.z + v.w);
        }
    }

    // wave reduction (64 lanes)
    #pragma unroll
    for (int off = 32; off > 0; off >>= 1)
        accl += __shfl_down(accl, off, 64);

    __shared__ float wsum[BLOCK / 64];
    if (lane == 0) wsum[wave] = accl;
    __syncthreads();
    if (threadIdx.x == 0) {
        float s = 0.0f;
        #pragma unroll
        for (int w = 0; w < BLOCK / 64; ++w) s += wsum[w];
        partials[blockIdx.x] = s;   // plain store: no atomics, no memset needed
    }
}

__global__ __launch_bounds__(256) void finalize_kernel(
    const float* __restrict__ partials, float* __restrict__ out)
{
    __shared__ double sh[256];
    double s = 0.0;
    for (int i = threadIdx.x; i < GRID; i += 256)
        s += (double)partials[i];
    sh[threadIdx.x] = s;
    __syncthreads();
    #pragma unroll
    for (int stride = 128; stride > 0; stride >>= 1) {
        if (threadIdx.x < stride) sh[threadIdx.x] += sh[threadIdx.x + stride];
        __syncthreads();
    }
    if (threadIdx.x == 0)
        out[0] = (float)(sh[0] / ((double)TOTAL * (double)EMB_DIM));
}

extern "C" void kernel_launch(void* const* d_in, const int* in_sizes, int n_in,
                              void* d_out, int out_size, void* d_ws, size_t ws_size,
                              hipStream_t stream) {
    const int*   ids0 = (const int*)d_in[0];
    const int*   ids1 = (const int*)d_in[1];
    const int*   mch0 = (const int*)d_in[2];
    const int*   mch1 = (const int*)d_in[3];
    const float* emb0 = (const float*)d_in[4];
    const float* emb1 = (const float*)d_in[5];

    float* out      = (float*)d_out;
    float* partials = (float*)d_ws;   // GRID floats = ~31 KB

    remap_loss_kernel<<<GRID, BLOCK, 0, stream>>>(
        ids0, ids1, mch0, mch1, emb0, emb1, out, partials);
    finalize_kernel<<<1, 256, 0, stream>>>(partials, out);
}

// Round 3
// 417.614 us; speedup vs baseline: 1.1793x; 1.1793x over previous
//
#include <hip/hip_runtime.h>
#include <stdint.h>

#define N_IDS   1000000
#define ZCH     400000
#define EMB_DIM 128
#define TOTAL   (2 * N_IDS)
#define BLOCK   256
#define GRID    ((TOTAL + BLOCK - 1) / BLOCK)   // 7813
#define BSHIFT  6
#define NBUCK   62500                // ids < 4,000,000  ->  id>>6 in [0, 62500)
#define OFFSZ   (NBUCK + 1)

// d_out is FLOAT32: [0] = loss, [1 .. 2M] = remapped indices as floats.
// d_ws layout: [off0: OFFSZ ints][off1: OFFSZ ints][partials: GRID floats]

__global__ __launch_bounds__(256) void build_offsets_kernel(
    const int* __restrict__ mch0, const int* __restrict__ mch1,
    int* __restrict__ off0, int* __restrict__ off1)
{
    int t = blockIdx.x * blockDim.x + threadIdx.x;
    if (t >= 2 * OFFSZ) return;
    const int feat = t >= OFFSZ;
    const int b    = feat ? (t - OFFSZ) : t;
    const int* __restrict__ mch = feat ? mch1 : mch0;
    int* __restrict__ off       = feat ? off1 : off0;
    const int target = b << BSHIFT;
    int lo = 0, hi = ZCH;
    #pragma unroll 1
    while (lo < hi) {
        int mid = (lo + hi) >> 1;
        if (mch[mid] < target) lo = mid + 1; else hi = mid;
    }
    off[b] = lo;
}

__global__ __launch_bounds__(BLOCK) void remap_loss_kernel(
    const int* __restrict__ ids0, const int* __restrict__ ids1,
    const int* __restrict__ mch0, const int* __restrict__ mch1,
    const float* __restrict__ emb0, const float* __restrict__ emb1,
    const int* __restrict__ off0, const int* __restrict__ off1,
    float* __restrict__ out,
    float* __restrict__ partials)
{
    const int gid  = blockIdx.x * BLOCK + threadIdx.x;
    const int lane = threadIdx.x & 63;
    const int wave = threadIdx.x >> 6;

    float accl = 0.0f;

    // Wave-uniform activity/feature: TOTAL % 64 == 0 and N_IDS % 64 == 0.
    const bool active = (gid < TOTAL);
    if (active) {
        const int feat = gid >= N_IDS;
        const int i    = feat ? (gid - N_IDS) : gid;
        const int id   = (feat ? ids1 : ids0)[i];
        const int* __restrict__ mch   = feat ? mch1 : mch0;
        const int* __restrict__ off   = feat ? off1 : off0;
        const float* __restrict__ emb = feat ? emb1 : emb0;

        // Bucketed lower_bound: entries < b*64 are all < id; entries >= (b+1)*64
        // are all > id, so global pos = off[b] + count of [off[b],off[b+1]) < id.
        const int b  = id >> BSHIFT;
        const int lo = off[b];
        const int hi = off[b + 1];
        int pos = lo;
        #pragma unroll 1
        for (int j = lo; j < hi; ++j)
            pos += (mch[j] < id);                  // independent loads, 1-2 lines

        int posc = (pos < ZCH) ? pos : (ZCH - 1);
        int rem  = (mch[posc] == id) ? posc : (ZCH - 1);

        out[1 + gid] = (float)rem;                 // exact: rem < 2^24

        // ---- loss: dedupe the overflow row (~90% of ids) ----
        const unsigned long long ovf = __ballot(rem == (ZCH - 1));
        const int novf = __popcll(ovf);

        if (novf) {
            const float2* __restrict__ row =
                (const float2*)(emb + (size_t)(ZCH - 1) * EMB_DIM);
            float2 v = row[lane];                  // L1-hot
            float s = v.x + v.y;
            #pragma unroll
            for (int o = 32; o > 0; o >>= 1)
                s += __shfl_xor(s, o, 64);         // full row sum on all lanes
            if (lane == 0) accl += (float)novf * s;
        }

        unsigned long long hits = ~ovf;            // all 64 lanes are valid ids
        #pragma unroll 1
        while (hits) {                             // wave-uniform mask
            int j = __ffsll(hits) - 1;
            hits &= hits - 1;
            int r = __shfl(rem, j, 64);
            const float2* __restrict__ row =
                (const float2*)(emb + (size_t)r * EMB_DIM);
            float2 v = row[lane];                  // 512 B coalesced per row
            accl += v.x + v.y;
        }
    }

    // wave reduction (64 lanes)
    #pragma unroll
    for (int o = 32; o > 0; o >>= 1)
        accl += __shfl_down(accl, o, 64);

    __shared__ float wsum[BLOCK / 64];
    if (lane == 0) wsum[wave] = accl;
    __syncthreads();
    if (threadIdx.x == 0) {
        float s = 0.0f;
        #pragma unroll
        for (int w = 0; w < BLOCK / 64; ++w) s += wsum[w];
        partials[blockIdx.x] = s;
    }
}

__global__ __launch_bounds__(256) void finalize_kernel(
    const float* __restrict__ partials, float* __restrict__ out)
{
    __shared__ double sh[256];
    double s = 0.0;
    for (int i = threadIdx.x; i < GRID; i += 256)
        s += (double)partials[i];
    sh[threadIdx.x] = s;
    __syncthreads();
    #pragma unroll
    for (int stride = 128; stride > 0; stride >>= 1) {
        if (threadIdx.x < stride) sh[threadIdx.x] += sh[threadIdx.x + stride];
        __syncthreads();
    }
    if (threadIdx.x == 0)
        out[0] = (float)(sh[0] / ((double)TOTAL * (double)EMB_DIM));
}

extern "C" void kernel_launch(void* const* d_in, const int* in_sizes, int n_in,
                              void* d_out, int out_size, void* d_ws, size_t ws_size,
                              hipStream_t stream) {
    const int*   ids0 = (const int*)d_in[0];
    const int*   ids1 = (const int*)d_in[1];
    const int*   mch0 = (const int*)d_in[2];
    const int*   mch1 = (const int*)d_in[3];
    const float* emb0 = (const float*)d_in[4];
    const float* emb1 = (const float*)d_in[5];

    float* out      = (float*)d_out;
    int*   off0     = (int*)d_ws;
    int*   off1     = off0 + OFFSZ;
    float* partials = (float*)(off1 + OFFSZ);

    build_offsets_kernel<<<(2 * OFFSZ + 255) / 256, 256, 0, stream>>>(
        mch0, mch1, off0, off1);
    remap_loss_kernel<<<GRID, BLOCK, 0, stream>>>(
        ids0, ids1, mch0, mch1, emb0, emb1, off0, off1, out, partials);
    finalize_kernel<<<1, 256, 0, stream>>>(partials, out);
}

// Round 4
// 382.485 us; speedup vs baseline: 1.2876x; 1.0918x over previous
//
#include <hip/hip_runtime.h>
#include <stdint.h>

#define N_IDS     1000000
#define ZCH       400000
#define EMB_DIM   128
#define TOTAL     (2 * N_IDS)
#define HASH_SZ   4000000            // id values are in [0, 4M)
#define BLOCK     256
#define GRID      ((TOTAL + BLOCK - 1) / BLOCK)   // 7813
#define OVF       (ZCH - 1)

// d_out (float32): [0] = loss, [1 .. 2M] = remapped indices as floats.
// d_ws layout: [lut0: 4M ints][lut1: 4M ints][partials: GRID floats]  (~32 MB)

__global__ __launch_bounds__(256) void init_lut_kernel(int4* __restrict__ lut)
{
    // 2 features x 4M ints = 8M ints = 2M int4 stores
    int t = blockIdx.x * blockDim.x + threadIdx.x;
    if (t < (2 * HASH_SZ) / 4)
        lut[t] = make_int4(OVF, OVF, OVF, OVF);
}

__global__ __launch_bounds__(256) void scatter_lut_kernel(
    const int* __restrict__ mch0, const int* __restrict__ mch1,
    int* __restrict__ lut0, int* __restrict__ lut1)
{
    int t = blockIdx.x * blockDim.x + threadIdx.x;
    if (t >= 2 * ZCH) return;
    const int feat = t >= ZCH;
    const int s    = feat ? (t - ZCH) : t;
    const int* __restrict__ mch = feat ? mch1 : mch0;
    int* __restrict__ lut       = feat ? lut1 : lut0;
    const int v = mch[s];
    // searchsorted-left: only the FIRST occurrence of a value owns the slot.
    if (s == 0 || mch[s - 1] != v)
        lut[v] = s;
}

__global__ __launch_bounds__(BLOCK) void remap_loss_kernel(
    const int* __restrict__ ids0, const int* __restrict__ ids1,
    const float* __restrict__ emb0, const float* __restrict__ emb1,
    const int* __restrict__ lut0, const int* __restrict__ lut1,
    float* __restrict__ out,
    float* __restrict__ partials)
{
    const int gid  = blockIdx.x * BLOCK + threadIdx.x;
    const int lane = threadIdx.x & 63;
    const int wave = threadIdx.x >> 6;

    float accl = 0.0f;

    // Wave-uniform activity/feature: TOTAL % 64 == 0 and N_IDS % 64 == 0.
    const bool active = (gid < TOTAL);
    if (active) {
        const int feat = gid >= N_IDS;
        const int i    = feat ? (gid - N_IDS) : gid;
        const int id   = (feat ? ids1 : ids0)[i];
        const float* __restrict__ emb = feat ? emb1 : emb0;

        const int rem = (feat ? lut1 : lut0)[id];   // the whole "search"

        out[1 + gid] = (float)rem;                  // exact: rem < 2^24

        // ---- loss ----
        // ~90.5% of ids hit the overflow row: dedupe it (L1-hot).
        const unsigned long long ovf = __ballot(rem == OVF);
        const int novf = __popcll(ovf);
        if (novf) {
            const float2* __restrict__ row =
                (const float2*)(emb + (size_t)OVF * EMB_DIM);
            float2 v = row[lane];                   // 64 x 8 B = one row
            float s = v.x + v.y;
            #pragma unroll
            for (int o = 32; o > 0; o >>= 1)
                s += __shfl_xor(s, o, 64);
            if (lane == 0) accl += (float)novf * s;
        }

        // Remaining ~6 distinct rows per wave: 2 rows/iteration,
        // half-wave x float4 (32 x 16 B = 512 B = one row).
        const int half = lane >> 5;
        const int l32  = lane & 31;
        unsigned long long hits = ~ovf;             // all 64 lanes are valid
        #pragma unroll 1
        while (hits) {                              // wave-uniform mask
            int j0 = __ffsll(hits) - 1;
            hits &= hits - 1;
            const bool dup = (hits == 0);           // odd count: duplicate j0
            int j1 = dup ? j0 : (__ffsll(hits) - 1);
            if (!dup) hits &= hits - 1;
            int r = __shfl(rem, half ? j1 : j0, 64);
            const float4* __restrict__ row =
                (const float4*)(emb + (size_t)r * EMB_DIM);
            float4 v = row[l32];
            float s4 = (v.x + v.y) + (v.z + v.w);
            accl += (half && dup) ? 0.0f : s4;      // drop the duplicated half
        }
    }

    // wave reduction (64 lanes)
    #pragma unroll
    for (int o = 32; o > 0; o >>= 1)
        accl += __shfl_down(accl, o, 64);

    __shared__ float wsum[BLOCK / 64];
    if (lane == 0) wsum[wave] = accl;
    __syncthreads();
    if (threadIdx.x == 0) {
        float s = 0.0f;
        #pragma unroll
        for (int w = 0; w < BLOCK / 64; ++w) s += wsum[w];
        partials[blockIdx.x] = s;
    }
}

__global__ __launch_bounds__(256) void finalize_kernel(
    const float* __restrict__ partials, float* __restrict__ out)
{
    __shared__ double sh[256];
    double s = 0.0;
    for (int i = threadIdx.x; i < GRID; i += 256)
        s += (double)partials[i];
    sh[threadIdx.x] = s;
    __syncthreads();
    #pragma unroll
    for (int stride = 128; stride > 0; stride >>= 1) {
        if (threadIdx.x < stride) sh[threadIdx.x] += sh[threadIdx.x + stride];
        __syncthreads();
    }
    if (threadIdx.x == 0)
        out[0] = (float)(sh[0] / ((double)TOTAL * (double)EMB_DIM));
}

extern "C" void kernel_launch(void* const* d_in, const int* in_sizes, int n_in,
                              void* d_out, int out_size, void* d_ws, size_t ws_size,
                              hipStream_t stream) {
    const int*   ids0 = (const int*)d_in[0];
    const int*   ids1 = (const int*)d_in[1];
    const int*   mch0 = (const int*)d_in[2];
    const int*   mch1 = (const int*)d_in[3];
    const float* emb0 = (const float*)d_in[4];
    const float* emb1 = (const float*)d_in[5];

    float* out      = (float*)d_out;
    int*   lut0     = (int*)d_ws;
    int*   lut1     = lut0 + HASH_SZ;
    float* partials = (float*)(lut1 + HASH_SZ);

    init_lut_kernel<<<((2 * HASH_SZ / 4) + 255) / 256, 256, 0, stream>>>(
        (int4*)d_ws);
    scatter_lut_kernel<<<(2 * ZCH + 255) / 256, 256, 0, stream>>>(
        mch0, mch1, lut0, lut1);
    remap_loss_kernel<<<GRID, BLOCK, 0, stream>>>(
        ids0, ids1, emb0, emb1, lut0, lut1, out, partials);
    finalize_kernel<<<1, 256, 0, stream>>>(partials, out);
}